// Round 2
// baseline (16295.229 us; speedup 1.0000x reference)
//
#include <hip/hip_runtime.h>
#include <math.h>

#define VOCAB 50000
#define DM 256
#define NB 8
#define NK 4
#define SL 24
#define NROW 32
#define DIVS 0.5f

// ctx[b][d] = mean_s(src[b,s,:]) @ We
__global__ void k_prep(const float* __restrict__ src, const float* __restrict__ We,
                       float* __restrict__ ctx) {
  int b = blockIdx.x, d = threadIdx.x;
  __shared__ float sm[DM];
  const float* p = src + (size_t)b * 128 * DM + d;
  float s = 0.f;
  for (int i = 0; i < 128; ++i) s += p[i * DM];
  sm[d] = s * (1.f / 128.f);
  __syncthreads();
  float acc = 0.f;
  for (int dp = 0; dp < DM; ++dp) acc += sm[dp] * We[dp * DM + d];
  ctx[b * DM + d] = acc;
}

// logits[r][v] = (Emb[tok_r] + ctx[r/4]) @ Wout[:,v]   (matches reference h @ Wout)
__global__ __launch_bounds__(256) void k_logits(
    const float* __restrict__ Emb, const float* __restrict__ Wout,
    const float* __restrict__ ctx, const int* __restrict__ seq,
    float* __restrict__ logits, int t) {
  __shared__ __align__(16) float e[NROW][DM];
  int tid = threadIdx.x;
  for (int r = 0; r < NROW; ++r) {
    int tok = seq[r * SL + (t - 1)];
    e[r][tid] = Emb[(size_t)tok * DM + tid] + ctx[(r >> 2) * DM + tid];
  }
  __syncthreads();
  int v = blockIdx.x * 256 + tid;
  if (v >= VOCAB) return;
  float acc[NROW];
#pragma unroll
  for (int r = 0; r < NROW; ++r) acc[r] = 0.f;
  for (int d = 0; d < DM; d += 4) {
    float w0 = Wout[(size_t)d * VOCAB + v];
    float w1 = Wout[(size_t)(d + 1) * VOCAB + v];
    float w2 = Wout[(size_t)(d + 2) * VOCAB + v];
    float w3 = Wout[(size_t)(d + 3) * VOCAB + v];
#pragma unroll
    for (int r = 0; r < NROW; ++r) {
      const float4 e4 = *reinterpret_cast<const float4*>(&e[r][d]);
      acc[r] = fmaf(e4.w, w3, fmaf(e4.z, w2, fmaf(e4.y, w1, fmaf(e4.x, w0, acc[r]))));
    }
  }
#pragma unroll
  for (int r = 0; r < NROW; ++r)
    logits[(size_t)r * VOCAB + v] = acc[r];
}

__global__ __launch_bounds__(1024) void k_lse(const float* __restrict__ logits,
                                              float* __restrict__ lse) {
  int r = blockIdx.x, tid = threadIdx.x;
  const float* row = logits + (size_t)r * VOCAB;
  __shared__ float red[1024];
  float m = -INFINITY;
  for (int v = tid; v < VOCAB; v += 1024) m = fmaxf(m, row[v]);
  red[tid] = m;
  __syncthreads();
  for (int s = 512; s > 0; s >>= 1) {
    if (tid < s) red[tid] = fmaxf(red[tid], red[tid + s]);
    __syncthreads();
  }
  float M = red[0];
  __syncthreads();
  float s = 0.f;
  for (int v = tid; v < VOCAB; v += 1024) s += expf(row[v] - M);
  red[tid] = s;
  __syncthreads();
  for (int st = 512; st > 0; st >>= 1) {
    if (tid < st) red[tid] += red[tid + st];
    __syncthreads();
  }
  if (tid == 0) lse[r] = M + logf(red[0]);
}

// Brute-force, reference-order top-4:
//   phase 1: cand[k*V+v] = gs[k] + ((logit - lse[k]) - pen)   (exact ref rounding order)
//   phase 2: 4 sequential argmax tree reductions, tie -> lower flat index, mask winner.
__global__ __launch_bounds__(1024) void k_topk(
    const float* __restrict__ logits, const float* __restrict__ lse,
    const float* __restrict__ gs_src, const int* __restrict__ seq_src,
    float* __restrict__ gs_dst, int* __restrict__ seq_dst,
    const int* __restrict__ minpos, float* __restrict__ cand,
    int t, int g, float* __restrict__ out) {
  int b = blockIdx.x, tid = threadIdx.x;
  float* cb = cand + (size_t)b * (NK * VOCAB);
  __shared__ float gsv[NK], lsev[NK];
  __shared__ int oldseq[NK * SL];
  __shared__ float rv[1024];
  __shared__ int ri[1024];
  __shared__ float selv[NK];
  __shared__ int selb[NK], selt[NK];
  if (tid < NK) { gsv[tid] = gs_src[b * NK + tid]; lsev[tid] = lse[b * NK + tid]; }
  if (tid < NK * SL) oldseq[tid] = seq_src[b * NK * SL + tid];
  __syncthreads();

  for (int k = 0; k < NK; ++k) {
    float gsk = gsv[k], lsek = lsev[k];
    const float* lrow = logits + (size_t)(b * NK + k) * VOCAB;
    const int* mp = minpos + (size_t)k * VOCAB;
    for (int v = tid; v < VOCAB; v += 1024) {
      float sc = lrow[v] - lsek;            // log_softmax (ref rounding)
      if (g && mp[v] < t) sc -= DIVS;       // diversity penalty (ref rounding)
      cb[k * VOCAB + v] = gsk + sc;         // total (ref rounding)
    }
  }
  __syncthreads();

  for (int j = 0; j < NK; ++j) {
    float bv = -INFINITY;
    int bi = 0x7fffffff;
    for (int i = tid; i < NK * VOCAB; i += 1024) {
      float x = cb[i];
      if (x > bv || (x == bv && i < bi)) { bv = x; bi = i; }
    }
    rv[tid] = bv; ri[tid] = bi;
    __syncthreads();
    for (int s = 512; s > 0; s >>= 1) {
      if (tid < s) {
        float xv = rv[tid + s]; int xi = ri[tid + s];
        if (xv > rv[tid] || (xv == rv[tid] && xi < ri[tid])) { rv[tid] = xv; ri[tid] = xi; }
      }
      __syncthreads();
    }
    if (tid == 0) {
      selv[j] = rv[0];
      selb[j] = ri[0] / VOCAB;
      selt[j] = ri[0] % VOCAB;
      cb[ri[0]] = -INFINITY;   // mask winner for next pass
    }
    __syncthreads();
  }

  if (tid < NK * SL) {
    int j = tid / SL, l = tid % SL;
    int tok = (l == t) ? selt[j] : oldseq[selb[j] * SL + l];
    seq_dst[b * NK * SL + tid] = tok;
    if (t == SL - 1) out[(size_t)b * (2 * NK * SL) + (g * NK + j) * SL + l] = (float)tok;
  }
  if (tid < NK) {
    gs_dst[b * NK + tid] = selv[tid];
    if (t == SL - 1) out[NB * 2 * NK * SL + b * (2 * NK) + g * NK + tid] = selv[tid];
  }
}

__global__ void k_init(int* __restrict__ seqA, float* __restrict__ gsA) {
  int i = threadIdx.x;  // 768 threads
  seqA[i] = (i % SL == 0) ? 1 : 0;
  if (i < NB * NK) gsA[i] = ((i & 3) == 0) ? 0.f : -1e9f;
}

__global__ void k_minpos_init(int* __restrict__ minpos) {
  int i = blockIdx.x * 256 + threadIdx.x;
  if (i < NK * VOCAB) minpos[i] = 1 << 30;
}

__global__ void k_minpos_scatter(const int* __restrict__ seq, int* __restrict__ minpos) {
  int i = threadIdx.x;  // 768 threads: (b*4+k)*24+l
  int l = i % SL;
  int k = (i / SL) % NK;
  int tok = seq[i];
  atomicMin(&minpos[(size_t)k * VOCAB + tok], l);
}

extern "C" void kernel_launch(void* const* d_in, const int* in_sizes, int n_in,
                              void* d_out, int out_size, void* d_ws, size_t ws_size,
                              hipStream_t stream) {
  (void)in_sizes; (void)n_in; (void)out_size; (void)ws_size;
  const float* src  = (const float*)d_in[0];
  const float* We   = (const float*)d_in[1];
  const float* Emb  = (const float*)d_in[2];
  const float* Wout = (const float*)d_in[3];
  float* out = (float*)d_out;
  char* ws = (char*)d_ws;
  size_t off = 0;
  auto carve = [&](size_t bytes) {
    char* p = ws + off;
    off += (bytes + 255) & ~(size_t)255;
    return p;
  };
  float* ctx    = (float*)carve((size_t)NB * DM * 4);
  float* logits = (float*)carve((size_t)NROW * VOCAB * 4);
  float* lse    = (float*)carve((size_t)NROW * 4);
  int*   seqA   = (int*)carve((size_t)NB * NK * SL * 4);
  int*   seqB   = (int*)carve((size_t)NB * NK * SL * 4);
  float* gsA    = (float*)carve((size_t)NROW * 4);
  float* gsB    = (float*)carve((size_t)NROW * 4);
  int*   minpos = (int*)carve((size_t)NK * VOCAB * 4);
  float* cand   = (float*)carve((size_t)NB * NK * VOCAB * 4);

  int vblocks = (VOCAB + 255) / 256;
  hipLaunchKernelGGL(k_prep, dim3(NB), dim3(DM), 0, stream, src, We, ctx);

  for (int g = 0; g < 2; ++g) {
    hipLaunchKernelGGL(k_init, dim3(1), dim3(768), 0, stream, seqA, gsA);
    for (int t = 1; t < SL; ++t) {
      int* ssrc = ((t - 1) & 1) ? seqB : seqA;
      int* sdst = (t & 1) ? seqB : seqA;
      float* gsrc = ((t - 1) & 1) ? gsB : gsA;
      float* gdst = (t & 1) ? gsB : gsA;
      hipLaunchKernelGGL(k_logits, dim3(vblocks), dim3(256), 0, stream,
                         Emb, Wout, ctx, ssrc, logits, t);
      hipLaunchKernelGGL(k_lse, dim3(NROW), dim3(1024), 0, stream, logits, lse);
      hipLaunchKernelGGL(k_topk, dim3(NB), dim3(1024), 0, stream,
                         logits, lse, gsrc, ssrc, gdst, sdst, minpos, cand, t, g, out);
    }
    if (g == 0) {
      hipLaunchKernelGGL(k_minpos_init, dim3((NK * VOCAB + 255) / 256), dim3(256), 0, stream, minpos);
      hipLaunchKernelGGL(k_minpos_scatter, dim3(1), dim3(768), 0, stream, seqB, minpos);
    }
  }
}

// Round 3
// 5416.472 us; speedup vs baseline: 3.0085x; 3.0085x over previous
//
#include <hip/hip_runtime.h>
#include <math.h>

#define VOCAB 50000
#define DM 256
#define NB 8
#define NK 4
#define SL 24
#define NROW 32
#define DIVS 0.5f
#define NCH 64
#define CHUNK 782   // ceil(50000/64)

__device__ __forceinline__ bool cbetter(float av, int ai, float bv, int bi) {
  return (av > bv) || (av == bv && ai < bi);
}

// merge two sorted-4 lists (value desc, idx asc) -> sorted-4
__device__ __forceinline__ void merge4(const float* av, const int* ai,
                                       const float* bv, const int* bi,
                                       float* rv, int* ri) {
  int x = 0, y = 0;
#pragma unroll
  for (int j = 0; j < 4; ++j) {
    bool ta = cbetter(av[x], ai[x], bv[y], bi[y]);
    rv[j] = ta ? av[x] : bv[y];
    ri[j] = ta ? ai[x] : bi[y];
    if (ta) ++x; else ++y;
  }
}

// ctx[b][d] = mean_s(src[b,s,:]) @ We
__global__ void k_prep(const float* __restrict__ src, const float* __restrict__ We,
                       float* __restrict__ ctx) {
  int b = blockIdx.x, d = threadIdx.x;
  __shared__ float sm[DM];
  const float* p = src + (size_t)b * 128 * DM + d;
  float s = 0.f;
  for (int i = 0; i < 128; ++i) s += p[i * DM];
  sm[d] = s * (1.f / 128.f);
  __syncthreads();
  float acc = 0.f;
  for (int dp = 0; dp < DM; ++dp) acc += sm[dp] * We[dp * DM + d];
  ctx[b * DM + d] = acc;
}

// logits[r][v] = (Emb[tok_r] + ctx[r/4]) @ Wout[:,v]
__global__ __launch_bounds__(256) void k_logits(
    const float* __restrict__ Emb, const float* __restrict__ Wout,
    const float* __restrict__ ctx, const int* __restrict__ seq,
    float* __restrict__ logits, int t) {
  __shared__ __align__(16) float e[NROW][DM];
  int tid = threadIdx.x;
  for (int r = 0; r < NROW; ++r) {
    int tok = seq[r * SL + (t - 1)];
    e[r][tid] = Emb[(size_t)tok * DM + tid] + ctx[(r >> 2) * DM + tid];
  }
  __syncthreads();
  int v = blockIdx.x * 256 + tid;
  if (v >= VOCAB) return;
  float acc[NROW];
#pragma unroll
  for (int r = 0; r < NROW; ++r) acc[r] = 0.f;
  for (int d = 0; d < DM; d += 4) {
    float w0 = Wout[(size_t)d * VOCAB + v];
    float w1 = Wout[(size_t)(d + 1) * VOCAB + v];
    float w2 = Wout[(size_t)(d + 2) * VOCAB + v];
    float w3 = Wout[(size_t)(d + 3) * VOCAB + v];
#pragma unroll
    for (int r = 0; r < NROW; ++r) {
      const float4 e4 = *reinterpret_cast<const float4*>(&e[r][d]);
      acc[r] = fmaf(e4.w, w3, fmaf(e4.z, w2, fmaf(e4.y, w1, fmaf(e4.x, w0, acc[r]))));
    }
  }
#pragma unroll
  for (int r = 0; r < NROW; ++r)
    logits[(size_t)r * VOCAB + v] = acc[r];
}

__global__ __launch_bounds__(1024) void k_lse(const float* __restrict__ logits,
                                              float* __restrict__ lse) {
  int r = blockIdx.x, tid = threadIdx.x;
  const float* row = logits + (size_t)r * VOCAB;
  __shared__ float red[1024];
  float m = -INFINITY;
  for (int v = tid; v < VOCAB; v += 1024) m = fmaxf(m, row[v]);
  red[tid] = m;
  __syncthreads();
  for (int s = 512; s > 0; s >>= 1) {
    if (tid < s) red[tid] = fmaxf(red[tid], red[tid + s]);
    __syncthreads();
  }
  float M = red[0];
  __syncthreads();
  float s = 0.f;
  for (int v = tid; v < VOCAB; v += 1024) s += expf(row[v] - M);
  red[tid] = s;
  __syncthreads();
  for (int st = 512; st > 0; st >>= 1) {
    if (tid < st) red[tid] += red[tid + st];
    __syncthreads();
  }
  if (tid == 0) lse[r] = M + logf(red[0]);
}

// Stage 1: grid (NB*NCH), 256 thr. Per-thread sorted-4 (exact ref arithmetic per
// candidate), then 8-level LDS merge tree -> chunk top-4.
__global__ __launch_bounds__(256) void k_topk_s1(
    const float* __restrict__ logits, const float* __restrict__ lse,
    const float* __restrict__ gs_src, const int* __restrict__ minpos,
    float* __restrict__ s1v, int* __restrict__ s1i, int t, int g) {
  int b = blockIdx.x / NCH, c = blockIdx.x % NCH, tid = threadIdx.x;
  int v0 = c * CHUNK, v1 = min(v0 + CHUNK, VOCAB);
  __shared__ float gsv[NK], lsev[NK];
  __shared__ float lv[256][4];
  __shared__ int li[256][4];
  if (tid < NK) { gsv[tid] = gs_src[b * NK + tid]; lsev[tid] = lse[b * NK + tid]; }
  __syncthreads();

  float tv[4]; int ti[4];
#pragma unroll
  for (int j = 0; j < 4; ++j) { tv[j] = -INFINITY; ti[j] = 0x7fffffff; }

  for (int k = 0; k < NK; ++k) {
    float gsk = gsv[k], lsek = lsev[k];
    const float* lrow = logits + (size_t)(b * NK + k) * VOCAB;
    const int* mp = minpos + (size_t)k * VOCAB;
    for (int v = v0 + tid; v < v1; v += 256) {
      float sc = lrow[v] - lsek;           // ref rounding
      if (g && mp[v] < t) sc -= DIVS;      // ref rounding
      float x = gsk + sc;                  // ref rounding
      int idx = k * VOCAB + v;
      if (cbetter(x, idx, tv[3], ti[3])) {
        int pos = 3;
        if (cbetter(x, idx, tv[2], ti[2])) { tv[3]=tv[2]; ti[3]=ti[2]; pos=2;
          if (cbetter(x, idx, tv[1], ti[1])) { tv[2]=tv[1]; ti[2]=ti[1]; pos=1;
            if (cbetter(x, idx, tv[0], ti[0])) { tv[1]=tv[0]; ti[1]=ti[0]; pos=0; } } }
        tv[pos] = x; ti[pos] = idx;
      }
    }
  }
#pragma unroll
  for (int j = 0; j < 4; ++j) { lv[tid][j] = tv[j]; li[tid][j] = ti[j]; }
  __syncthreads();
  for (int s = 128; s >= 1; s >>= 1) {
    if (tid < s) {
      float av[4], bv[4], rv[4]; int ai[4], bi[4], ri[4];
#pragma unroll
      for (int j = 0; j < 4; ++j) { av[j]=lv[tid][j]; ai[j]=li[tid][j]; bv[j]=lv[tid+s][j]; bi[j]=li[tid+s][j]; }
      merge4(av, ai, bv, bi, rv, ri);
#pragma unroll
      for (int j = 0; j < 4; ++j) { lv[tid][j]=rv[j]; li[tid][j]=ri[j]; }
    }
    __syncthreads();
  }
  if (tid == 0) {
#pragma unroll
    for (int j = 0; j < 4; ++j) {
      s1v[(b * NCH + c) * 4 + j] = lv[0][j];
      s1i[(b * NCH + c) * 4 + j] = li[0][j];
    }
  }
}

// Stage 2: grid NB, 128 thr. Merge 64 sorted-4 lists -> top-4, then gather/update.
__global__ __launch_bounds__(128) void k_topk_s2(
    const float* __restrict__ s1v, const int* __restrict__ s1i,
    const int* __restrict__ seq_src, float* __restrict__ gs_dst,
    int* __restrict__ seq_dst, int t, int g, float* __restrict__ out) {
  int b = blockIdx.x, tid = threadIdx.x;
  __shared__ float lv[NCH][4];
  __shared__ int li[NCH][4];
  __shared__ int oldseq[NK * SL];
  __shared__ float selv[NK];
  __shared__ int selb[NK], selt[NK];
  if (tid < NCH) {
#pragma unroll
    for (int j = 0; j < 4; ++j) { lv[tid][j] = s1v[(b * NCH + tid) * 4 + j]; li[tid][j] = s1i[(b * NCH + tid) * 4 + j]; }
  }
  if (tid < NK * SL) oldseq[tid] = seq_src[b * NK * SL + tid];
  __syncthreads();
  for (int s = 32; s >= 1; s >>= 1) {
    if (tid < s) {
      float av[4], bv[4], rv[4]; int ai[4], bi[4], ri[4];
#pragma unroll
      for (int j = 0; j < 4; ++j) { av[j]=lv[tid][j]; ai[j]=li[tid][j]; bv[j]=lv[tid+s][j]; bi[j]=li[tid+s][j]; }
      merge4(av, ai, bv, bi, rv, ri);
#pragma unroll
      for (int j = 0; j < 4; ++j) { lv[tid][j]=rv[j]; li[tid][j]=ri[j]; }
    }
    __syncthreads();
  }
  if (tid == 0) {
#pragma unroll
    for (int j = 0; j < 4; ++j) {
      selv[j] = lv[0][j];
      selb[j] = li[0][j] / VOCAB;
      selt[j] = li[0][j] % VOCAB;
    }
  }
  __syncthreads();
  if (tid < NK * SL) {
    int j = tid / SL, l = tid % SL;
    int tok = (l == t) ? selt[j] : oldseq[selb[j] * SL + l];
    seq_dst[b * NK * SL + tid] = tok;
    if (t == SL - 1) out[(size_t)b * (2 * NK * SL) + (g * NK + j) * SL + l] = (float)tok;
  }
  if (tid < NK) {
    gs_dst[b * NK + tid] = selv[tid];
    if (t == SL - 1) out[NB * 2 * NK * SL + b * (2 * NK) + g * NK + tid] = selv[tid];
  }
}

__global__ void k_init(int* __restrict__ seqA, float* __restrict__ gsA) {
  int i = threadIdx.x;  // 768 threads
  seqA[i] = (i % SL == 0) ? 1 : 0;
  if (i < NB * NK) gsA[i] = ((i & 3) == 0) ? 0.f : -1e9f;
}

__global__ void k_minpos_init(int* __restrict__ minpos) {
  int i = blockIdx.x * 256 + threadIdx.x;
  if (i < NK * VOCAB) minpos[i] = 1 << 30;
}

__global__ void k_minpos_scatter(const int* __restrict__ seq, int* __restrict__ minpos) {
  int i = threadIdx.x;  // 768 threads
  int l = i % SL;
  int k = (i / SL) % NK;
  int tok = seq[i];
  atomicMin(&minpos[(size_t)k * VOCAB + tok], l);
}

extern "C" void kernel_launch(void* const* d_in, const int* in_sizes, int n_in,
                              void* d_out, int out_size, void* d_ws, size_t ws_size,
                              hipStream_t stream) {
  (void)in_sizes; (void)n_in; (void)out_size; (void)ws_size;
  const float* src  = (const float*)d_in[0];
  const float* We   = (const float*)d_in[1];
  const float* Emb  = (const float*)d_in[2];
  const float* Wout = (const float*)d_in[3];
  float* out = (float*)d_out;
  char* ws = (char*)d_ws;
  size_t off = 0;
  auto carve = [&](size_t bytes) {
    char* p = ws + off;
    off += (bytes + 255) & ~(size_t)255;
    return p;
  };
  float* ctx    = (float*)carve((size_t)NB * DM * 4);
  float* logits = (float*)carve((size_t)NROW * VOCAB * 4);
  float* lse    = (float*)carve((size_t)NROW * 4);
  int*   seqA   = (int*)carve((size_t)NB * NK * SL * 4);
  int*   seqB   = (int*)carve((size_t)NB * NK * SL * 4);
  float* gsA    = (float*)carve((size_t)NROW * 4);
  float* gsB    = (float*)carve((size_t)NROW * 4);
  int*   minpos = (int*)carve((size_t)NK * VOCAB * 4);
  float* s1v    = (float*)carve((size_t)NB * NCH * 4 * 4);
  int*   s1i    = (int*)carve((size_t)NB * NCH * 4 * 4);

  int vblocks = (VOCAB + 255) / 256;
  hipLaunchKernelGGL(k_prep, dim3(NB), dim3(DM), 0, stream, src, We, ctx);

  for (int g = 0; g < 2; ++g) {
    hipLaunchKernelGGL(k_init, dim3(1), dim3(768), 0, stream, seqA, gsA);
    for (int t = 1; t < SL; ++t) {
      int* ssrc = ((t - 1) & 1) ? seqB : seqA;
      int* sdst = (t & 1) ? seqB : seqA;
      float* gsrc = ((t - 1) & 1) ? gsB : gsA;
      float* gdst = (t & 1) ? gsB : gsA;
      hipLaunchKernelGGL(k_logits, dim3(vblocks), dim3(256), 0, stream,
                         Emb, Wout, ctx, ssrc, logits, t);
      hipLaunchKernelGGL(k_lse, dim3(NROW), dim3(1024), 0, stream, logits, lse);
      hipLaunchKernelGGL(k_topk_s1, dim3(NB * NCH), dim3(256), 0, stream,
                         logits, lse, gsrc, minpos, s1v, s1i, t, g);
      hipLaunchKernelGGL(k_topk_s2, dim3(NB), dim3(128), 0, stream,
                         s1v, s1i, ssrc, gdst, sdst, t, g, out);
    }
    if (g == 0) {
      hipLaunchKernelGGL(k_minpos_init, dim3((NK * VOCAB + 255) / 256), dim3(256), 0, stream, minpos);
      hipLaunchKernelGGL(k_minpos_scatter, dim3(1), dim3(768), 0, stream, seqB, minpos);
    }
  }
}

// Round 4
// 3487.574 us; speedup vs baseline: 4.6724x; 1.5531x over previous
//
#include <hip/hip_runtime.h>
#include <math.h>

#define VOCAB 50000
#define DM 256
#define NB 8
#define NK 4
#define SL 24
#define NROW 32
#define RG 8          // rows per block (row-group)
#define NRG (NROW/RG) // 4 row-groups
#define DIVS 0.5f
#define NCH 64
#define CHUNK 782   // ceil(50000/64)

__device__ __forceinline__ bool cbetter(float av, int ai, float bv, int bi) {
  return (av > bv) || (av == bv && ai < bi);
}

// merge two sorted-4 lists (value desc, idx asc) -> sorted-4
__device__ __forceinline__ void merge4(const float* av, const int* ai,
                                       const float* bv, const int* bi,
                                       float* rv, int* ri) {
  int x = 0, y = 0;
#pragma unroll
  for (int j = 0; j < 4; ++j) {
    bool ta = cbetter(av[x], ai[x], bv[y], bi[y]);
    rv[j] = ta ? av[x] : bv[y];
    ri[j] = ta ? ai[x] : bi[y];
    if (ta) ++x; else ++y;
  }
}

// ctx[b][d] = mean_s(src[b,s,:]) @ We
__global__ void k_prep(const float* __restrict__ src, const float* __restrict__ We,
                       float* __restrict__ ctx) {
  int b = blockIdx.x, d = threadIdx.x;
  __shared__ float sm[DM];
  const float* p = src + (size_t)b * 128 * DM + d;
  float s = 0.f;
  for (int i = 0; i < 128; ++i) s += p[i * DM];
  sm[d] = s * (1.f / 128.f);
  __syncthreads();
  float acc = 0.f;
  for (int dp = 0; dp < DM; ++dp) acc += sm[dp] * We[dp * DM + d];
  ctx[b * DM + d] = acc;
}

// logits[r][v] = (Emb[tok_r] + ctx[r/4]) @ Wout[:,v]
// grid (vblocks, NRG): blockIdx.y picks 8 rows -> 784 blocks for occupancy.
// FMA chain per (r,v) identical to the 32-row version -> bit-identical logits.
__global__ __launch_bounds__(256) void k_logits(
    const float* __restrict__ Emb, const float* __restrict__ Wout,
    const float* __restrict__ ctx, const int* __restrict__ seq,
    float* __restrict__ logits, int t) {
  __shared__ __align__(16) float e[RG][DM];
  int tid = threadIdx.x;
  int rg = blockIdx.y;
  for (int r = 0; r < RG; ++r) {
    int rglob = rg * RG + r;
    int tok = seq[rglob * SL + (t - 1)];
    e[r][tid] = Emb[(size_t)tok * DM + tid] + ctx[(rglob >> 2) * DM + tid];
  }
  __syncthreads();
  int v = blockIdx.x * 256 + tid;
  if (v >= VOCAB) return;
  float acc[RG];
#pragma unroll
  for (int r = 0; r < RG; ++r) acc[r] = 0.f;
  for (int d = 0; d < DM; d += 4) {
    float w0 = Wout[(size_t)d * VOCAB + v];
    float w1 = Wout[(size_t)(d + 1) * VOCAB + v];
    float w2 = Wout[(size_t)(d + 2) * VOCAB + v];
    float w3 = Wout[(size_t)(d + 3) * VOCAB + v];
#pragma unroll
    for (int r = 0; r < RG; ++r) {
      const float4 e4 = *reinterpret_cast<const float4*>(&e[r][d]);
      acc[r] = fmaf(e4.w, w3, fmaf(e4.z, w2, fmaf(e4.y, w1, fmaf(e4.x, w0, acc[r]))));
    }
  }
#pragma unroll
  for (int r = 0; r < RG; ++r)
    logits[(size_t)(rg * RG + r) * VOCAB + v] = acc[r];
}

__global__ __launch_bounds__(1024) void k_lse(const float* __restrict__ logits,
                                              float* __restrict__ lse) {
  int r = blockIdx.x, tid = threadIdx.x;
  const float* row = logits + (size_t)r * VOCAB;
  __shared__ float red[1024];
  float m = -INFINITY;
  for (int v = tid; v < VOCAB; v += 1024) m = fmaxf(m, row[v]);
  red[tid] = m;
  __syncthreads();
  for (int s = 512; s > 0; s >>= 1) {
    if (tid < s) red[tid] = fmaxf(red[tid], red[tid + s]);
    __syncthreads();
  }
  float M = red[0];
  __syncthreads();
  float s = 0.f;
  for (int v = tid; v < VOCAB; v += 1024) s += expf(row[v] - M);
  red[tid] = s;
  __syncthreads();
  for (int st = 512; st > 0; st >>= 1) {
    if (tid < st) red[tid] += red[tid + st];
    __syncthreads();
  }
  if (tid == 0) lse[r] = M + logf(red[0]);
}

// Stage 1: grid (NB*NCH), 256 thr. Per-thread sorted-4 (exact ref arithmetic per
// candidate), then 8-level LDS merge tree -> chunk top-4.
__global__ __launch_bounds__(256) void k_topk_s1(
    const float* __restrict__ logits, const float* __restrict__ lse,
    const float* __restrict__ gs_src, const int* __restrict__ minpos,
    float* __restrict__ s1v, int* __restrict__ s1i, int t, int g) {
  int b = blockIdx.x / NCH, c = blockIdx.x % NCH, tid = threadIdx.x;
  int v0 = c * CHUNK, v1 = min(v0 + CHUNK, VOCAB);
  __shared__ float gsv[NK], lsev[NK];
  __shared__ float lv[256][4];
  __shared__ int li[256][4];
  if (tid < NK) { gsv[tid] = gs_src[b * NK + tid]; lsev[tid] = lse[b * NK + tid]; }
  __syncthreads();

  float tv[4]; int ti[4];
#pragma unroll
  for (int j = 0; j < 4; ++j) { tv[j] = -INFINITY; ti[j] = 0x7fffffff; }

  for (int k = 0; k < NK; ++k) {
    float gsk = gsv[k], lsek = lsev[k];
    const float* lrow = logits + (size_t)(b * NK + k) * VOCAB;
    const int* mp = minpos + (size_t)k * VOCAB;
    for (int v = v0 + tid; v < v1; v += 256) {
      float sc = lrow[v] - lsek;           // ref rounding
      if (g && mp[v] < t) sc -= DIVS;      // ref rounding
      float x = gsk + sc;                  // ref rounding
      int idx = k * VOCAB + v;
      if (cbetter(x, idx, tv[3], ti[3])) {
        int pos = 3;
        if (cbetter(x, idx, tv[2], ti[2])) { tv[3]=tv[2]; ti[3]=ti[2]; pos=2;
          if (cbetter(x, idx, tv[1], ti[1])) { tv[2]=tv[1]; ti[2]=ti[1]; pos=1;
            if (cbetter(x, idx, tv[0], ti[0])) { tv[1]=tv[0]; ti[1]=ti[0]; pos=0; } } }
        tv[pos] = x; ti[pos] = idx;
      }
    }
  }
#pragma unroll
  for (int j = 0; j < 4; ++j) { lv[tid][j] = tv[j]; li[tid][j] = ti[j]; }
  __syncthreads();
  for (int s = 128; s >= 1; s >>= 1) {
    if (tid < s) {
      float av[4], bv[4], rv[4]; int ai[4], bi[4], ri[4];
#pragma unroll
      for (int j = 0; j < 4; ++j) { av[j]=lv[tid][j]; ai[j]=li[tid][j]; bv[j]=lv[tid+s][j]; bi[j]=li[tid+s][j]; }
      merge4(av, ai, bv, bi, rv, ri);
#pragma unroll
      for (int j = 0; j < 4; ++j) { lv[tid][j]=rv[j]; li[tid][j]=ri[j]; }
    }
    __syncthreads();
  }
  if (tid == 0) {
#pragma unroll
    for (int j = 0; j < 4; ++j) {
      s1v[(b * NCH + c) * 4 + j] = lv[0][j];
      s1i[(b * NCH + c) * 4 + j] = li[0][j];
    }
  }
}

// Stage 2: grid NB, 128 thr. Merge 64 sorted-4 lists -> top-4, then gather/update.
__global__ __launch_bounds__(128) void k_topk_s2(
    const float* __restrict__ s1v, const int* __restrict__ s1i,
    const int* __restrict__ seq_src, float* __restrict__ gs_dst,
    int* __restrict__ seq_dst, int t, int g, float* __restrict__ out) {
  int b = blockIdx.x, tid = threadIdx.x;
  __shared__ float lv[NCH][4];
  __shared__ int li[NCH][4];
  __shared__ int oldseq[NK * SL];
  __shared__ float selv[NK];
  __shared__ int selb[NK], selt[NK];
  if (tid < NCH) {
#pragma unroll
    for (int j = 0; j < 4; ++j) { lv[tid][j] = s1v[(b * NCH + tid) * 4 + j]; li[tid][j] = s1i[(b * NCH + tid) * 4 + j]; }
  }
  if (tid < NK * SL) oldseq[tid] = seq_src[b * NK * SL + tid];
  __syncthreads();
  for (int s = 32; s >= 1; s >>= 1) {
    if (tid < s) {
      float av[4], bv[4], rv[4]; int ai[4], bi[4], ri[4];
#pragma unroll
      for (int j = 0; j < 4; ++j) { av[j]=lv[tid][j]; ai[j]=li[tid][j]; bv[j]=lv[tid+s][j]; bi[j]=li[tid+s][j]; }
      merge4(av, ai, bv, bi, rv, ri);
#pragma unroll
      for (int j = 0; j < 4; ++j) { lv[tid][j]=rv[j]; li[tid][j]=ri[j]; }
    }
    __syncthreads();
  }
  if (tid == 0) {
#pragma unroll
    for (int j = 0; j < 4; ++j) {
      selv[j] = lv[0][j];
      selb[j] = li[0][j] / VOCAB;
      selt[j] = li[0][j] % VOCAB;
    }
  }
  __syncthreads();
  if (tid < NK * SL) {
    int j = tid / SL, l = tid % SL;
    int tok = (l == t) ? selt[j] : oldseq[selb[j] * SL + l];
    seq_dst[b * NK * SL + tid] = tok;
    if (t == SL - 1) out[(size_t)b * (2 * NK * SL) + (g * NK + j) * SL + l] = (float)tok;
  }
  if (tid < NK) {
    gs_dst[b * NK + tid] = selv[tid];
    if (t == SL - 1) out[NB * 2 * NK * SL + b * (2 * NK) + g * NK + tid] = selv[tid];
  }
}

__global__ void k_init(int* __restrict__ seqA, float* __restrict__ gsA) {
  int i = threadIdx.x;  // 768 threads
  seqA[i] = (i % SL == 0) ? 1 : 0;
  if (i < NB * NK) gsA[i] = ((i & 3) == 0) ? 0.f : -1e9f;
}

__global__ void k_minpos_init(int* __restrict__ minpos) {
  int i = blockIdx.x * 256 + threadIdx.x;
  if (i < NK * VOCAB) minpos[i] = 1 << 30;
}

__global__ void k_minpos_scatter(const int* __restrict__ seq, int* __restrict__ minpos) {
  int i = threadIdx.x;  // 768 threads
  int l = i % SL;
  int k = (i / SL) % NK;
  int tok = seq[i];
  atomicMin(&minpos[(size_t)k * VOCAB + tok], l);
}

extern "C" void kernel_launch(void* const* d_in, const int* in_sizes, int n_in,
                              void* d_out, int out_size, void* d_ws, size_t ws_size,
                              hipStream_t stream) {
  (void)in_sizes; (void)n_in; (void)out_size; (void)ws_size;
  const float* src  = (const float*)d_in[0];
  const float* We   = (const float*)d_in[1];
  const float* Emb  = (const float*)d_in[2];
  const float* Wout = (const float*)d_in[3];
  float* out = (float*)d_out;
  char* ws = (char*)d_ws;
  size_t off = 0;
  auto carve = [&](size_t bytes) {
    char* p = ws + off;
    off += (bytes + 255) & ~(size_t)255;
    return p;
  };
  float* ctx    = (float*)carve((size_t)NB * DM * 4);
  float* logits = (float*)carve((size_t)NROW * VOCAB * 4);
  float* lse    = (float*)carve((size_t)NROW * 4);
  int*   seqA   = (int*)carve((size_t)NB * NK * SL * 4);
  int*   seqB   = (int*)carve((size_t)NB * NK * SL * 4);
  float* gsA    = (float*)carve((size_t)NROW * 4);
  float* gsB    = (float*)carve((size_t)NROW * 4);
  int*   minpos = (int*)carve((size_t)NK * VOCAB * 4);
  float* s1v    = (float*)carve((size_t)NB * NCH * 4 * 4);
  int*   s1i    = (int*)carve((size_t)NB * NCH * 4 * 4);

  int vblocks = (VOCAB + 255) / 256;
  hipLaunchKernelGGL(k_prep, dim3(NB), dim3(DM), 0, stream, src, We, ctx);

  for (int g = 0; g < 2; ++g) {
    hipLaunchKernelGGL(k_init, dim3(1), dim3(768), 0, stream, seqA, gsA);
    for (int t = 1; t < SL; ++t) {
      int* ssrc = ((t - 1) & 1) ? seqB : seqA;
      int* sdst = (t & 1) ? seqB : seqA;
      float* gsrc = ((t - 1) & 1) ? gsB : gsA;
      float* gdst = (t & 1) ? gsB : gsA;
      hipLaunchKernelGGL(k_logits, dim3(vblocks, NRG), dim3(256), 0, stream,
                         Emb, Wout, ctx, ssrc, logits, t);
      hipLaunchKernelGGL(k_lse, dim3(NROW), dim3(1024), 0, stream, logits, lse);
      hipLaunchKernelGGL(k_topk_s1, dim3(NB * NCH), dim3(256), 0, stream,
                         logits, lse, gsrc, minpos, s1v, s1i, t, g);
      hipLaunchKernelGGL(k_topk_s2, dim3(NB), dim3(128), 0, stream,
                         s1v, s1i, ssrc, gdst, sdst, t, g, out);
    }
    if (g == 0) {
      hipLaunchKernelGGL(k_minpos_init, dim3((NK * VOCAB + 255) / 256), dim3(256), 0, stream, minpos);
      hipLaunchKernelGGL(k_minpos_scatter, dim3(1), dim3(768), 0, stream, seqB, minpos);
    }
  }
}